// Round 6
// baseline (285.569 us; speedup 1.0000x reference)
//
#include <hip/hip_runtime.h>
#include <hip/hip_bf16.h>
#include <cstdint>
#include <cstddef>

#define NB_B 8
#define NB_N 2048
#define NB_C 128
#define NB_H 4
#define NB_D 32
#define NB_S1 3
#define NB_K 16
#define NB_KT 48
#define INV_SQRT_D 0.17677669529663688f

// ---- DPP reduce helpers: 16-lane group reduce, all-VALU (no DS ops) -------
#define DPP_F(x, ctrl) \
  __int_as_float(__builtin_amdgcn_update_dpp(0, __float_as_int(x), ctrl, 0xF, 0xF, true))

// ds_swizzle xor within 32-lane group: offset = (xor<<10) | 0x1F
#define SWZ_F(x, imm) \
  __int_as_float(__builtin_amdgcn_ds_swizzle(__float_as_int(x), imm))

__device__ __forceinline__ float sum16(float x) {
  x += DPP_F(x, 0xB1);
  x += DPP_F(x, 0x4E);
  x += DPP_F(x, 0x141);
  x += DPP_F(x, 0x140);
  return x;
}
__device__ __forceinline__ float max16(float x) {
  x = fmaxf(x, DPP_F(x, 0xB1));
  x = fmaxf(x, DPP_F(x, 0x4E));
  x = fmaxf(x, DPP_F(x, 0x141));
  x = fmaxf(x, DPP_F(x, 0x140));
  return x;
}

// u64 min step with DPP'd partner (within 16-lane rows) — used by fallback
#define DPP_MIN64(g, ctrl)                                                        \
  {                                                                               \
    unsigned int lo_ = (unsigned int)(g), hi_ = (unsigned int)((g) >> 32);        \
    unsigned int l2_ =                                                            \
        (unsigned int)__builtin_amdgcn_update_dpp(0, (int)lo_, ctrl, 0xF, 0xF, true); \
    unsigned int h2_ =                                                            \
        (unsigned int)__builtin_amdgcn_update_dpp(0, (int)hi_, ctrl, 0xF, 0xF, true); \
    unsigned long long o_ = ((unsigned long long)h2_ << 32) | l2_;                \
    if (o_ < (g)) (g) = o_;                                                       \
  }

__device__ __forceinline__ unsigned long long u64min(unsigned long long a,
                                                     unsigned long long b) {
  return a < b ? a : b;
}
__device__ __forceinline__ unsigned long long u64max(unsigned long long a,
                                                     unsigned long long b) {
  return a > b ? a : b;
}

// Canonical bitonic sort of 128 u64 across a wave (2 elements/lane,
// global index = 2*lane + r), ascending. 28 steps: 7 in-lane, 21 cross-lane.
__device__ __forceinline__ void bitonic128(unsigned long long& v0,
                                           unsigned long long& v1, int L) {
#pragma unroll
  for (int k = 2; k <= 128; k <<= 1) {
#pragma unroll
    for (int j = k >> 1; j > 0; j >>= 1) {
      bool up = ((L & (k >> 1)) == 0);
      if (j == 1) {
        unsigned long long lo = u64min(v0, v1), hi = u64max(v0, v1);
        v0 = up ? lo : hi;
        v1 = up ? hi : lo;
      } else {
        int lx = j >> 1;
        unsigned long long o0 = __shfl_xor(v0, lx);
        unsigned long long o1 = __shfl_xor(v1, lx);
        bool keepmin = (((L & lx) == 0) == up);
        v0 = keepmin ? u64min(v0, o0) : u64max(v0, o0);
        v1 = keepmin ? u64min(v1, o1) : u64max(v1, o1);
      }
    }
  }
}

// bottom-2 of the union of two sorted pairs (a0<=a1, b0<=b1)
#define BOT2(r0, r1, a0, a1, b0, b1)                          \
  {                                                           \
    r0 = u64min(a0, b0);                                      \
    r1 = u64min(u64max(a0, b0), (a0 < b0) ? (a1) : (b1));     \
  }

// ---------------------------------------------------------------------------
// prep: sq[b,n] = |coord|^2  and  WkT[i][col][c] = Wk[i][c][col]
// ---------------------------------------------------------------------------
__global__ __launch_bounds__(256) void prep_kernel(const float* __restrict__ coord,
                                                   const float* __restrict__ Wk,
                                                   float* __restrict__ sq,
                                                   float* __restrict__ wkT) {
  int tid = blockIdx.x * 256 + threadIdx.x;
  if (tid < NB_B * NB_N) {
    float x = coord[tid * 3 + 0], y = coord[tid * 3 + 1], z = coord[tid * 3 + 2];
    sq[tid] = x * x + y * y + z * z;
  }
  if (tid < NB_S1 * NB_C * NB_C) {
    int i = tid >> 14;          // / 16384
    int rem = tid & 16383;
    int col = rem >> 7, c = rem & 127;
    wkT[tid] = Wk[i * 16384 + c * 128 + col];
  }
}

// ---------------------------------------------------------------------------
// topk3: ONE WAVE per point (frozen — passed rounds 5).
// ---------------------------------------------------------------------------
__global__ __launch_bounds__(256) void topk3_kernel(const float* __restrict__ coord,
                                                    const float* __restrict__ sq,
                                                    int* __restrict__ idx_out) {
  __shared__ unsigned long long srv[4][128];   // per-wave survivor buffer (4 KB)
  const int t = threadIdx.x;
  const int w = t >> 6, l = t & 63;
  const int bn = blockIdx.x * 4 + w;          // one wave per point
  const int b = bn >> 11, n = bn & 2047;
  const float* cb = coord + (size_t)b * NB_N * 3;
  const float* sqb = sq + b * NB_N;

  const float cx = cb[n * 3 + 0], cy = cb[n * 3 + 1], cz = cb[n * 3 + 2];
  const float sqn = sqb[n];

  unsigned long long c0[8], c1[8], c2[8], c3[8];
#define DIST_KEY(dst, it)                                                     \
  {                                                                           \
    int m = (it) * 64 + l;                                                    \
    float mx = cb[m * 3 + 0], my = cb[m * 3 + 1], mz = cb[m * 3 + 2];         \
    float d = sqn + sqb[m] - 2.f * (cx * mx + cy * my + cz * mz);             \
    unsigned int db = __float_as_uint(d);                                     \
    unsigned int key = (db & 0x80000000u) ? ~db : (db | 0x80000000u);         \
    dst = ((unsigned long long)key << 32) | (unsigned int)m;                  \
  }
#pragma unroll
  for (int it = 0; it < 8; ++it) DIST_KEY(c0[it], it)
#pragma unroll
  for (int it = 0; it < 8; ++it) DIST_KEY(c1[it], 8 + it)
#pragma unroll
  for (int it = 0; it < 8; ++it) DIST_KEY(c2[it], 16 + it)
#pragma unroll
  for (int it = 0; it < 8; ++it) DIST_KEY(c3[it], 24 + it)
#undef DIST_KEY

#define CE(A, a, b)                                           \
  {                                                           \
    if (A[a] > A[b]) {                                        \
      unsigned long long tmp_ = A[a];                         \
      A[a] = A[b];                                            \
      A[b] = tmp_;                                            \
    }                                                         \
  }
#define SORT8(A)                                              \
  CE(A, 0, 1) CE(A, 2, 3) CE(A, 4, 5) CE(A, 6, 7)             \
  CE(A, 0, 2) CE(A, 1, 3) CE(A, 4, 6) CE(A, 5, 7)             \
  CE(A, 1, 2) CE(A, 5, 6)                                     \
  CE(A, 0, 4) CE(A, 1, 5) CE(A, 2, 6) CE(A, 3, 7)             \
  CE(A, 2, 4) CE(A, 3, 5)                                     \
  CE(A, 1, 2) CE(A, 3, 4) CE(A, 5, 6)
  SORT8(c0) SORT8(c1) SORT8(c2) SORT8(c3)
#undef SORT8
#undef CE

  // ---- per-lane two smallest (lists are sorted -> among first two of each) --
  unsigned long long x0, x1, y0, y1, m1, m2;
  BOT2(x0, x1, c0[0], c0[1], c1[0], c1[1])
  BOT2(y0, y1, c2[0], c2[1], c3[0], c3[1])
  BOT2(m1, m2, x0, x1, y0, y1)

  // ---- T = 48th smallest of the 128 samples ----
  unsigned long long v0 = m1, v1 = m2;
  bitonic128(v0, v1, l);
  const unsigned long long T = __shfl(v1, 23);   // global element #47

  // ---- count candidates <= T, wave prefix scan ----
  int cnt = 0;
#pragma unroll
  for (int j = 0; j < 8; ++j) cnt += (c0[j] <= T) ? 1 : 0;
#pragma unroll
  for (int j = 0; j < 8; ++j) cnt += (c1[j] <= T) ? 1 : 0;
#pragma unroll
  for (int j = 0; j < 8; ++j) cnt += (c2[j] <= T) ? 1 : 0;
#pragma unroll
  for (int j = 0; j < 8; ++j) cnt += (c3[j] <= T) ? 1 : 0;
  int inc = cnt;
#pragma unroll
  for (int off = 1; off < 64; off <<= 1) {
    int y = __shfl_up(inc, off);
    if (l >= off) inc += y;
  }
  const int M = __shfl(inc, 63);
  const int excl = inc - cnt;

  if (M <= 128) {
    srv[w][l] = ~0ULL;
    srv[w][l + 64] = ~0ULL;
    int k = excl;
#pragma unroll
    for (int j = 0; j < 8; ++j)
      if (c0[j] <= T) { srv[w][k] = c0[j]; ++k; }
#pragma unroll
    for (int j = 0; j < 8; ++j)
      if (c1[j] <= T) { srv[w][k] = c1[j]; ++k; }
#pragma unroll
    for (int j = 0; j < 8; ++j)
      if (c2[j] <= T) { srv[w][k] = c2[j]; ++k; }
#pragma unroll
    for (int j = 0; j < 8; ++j)
      if (c3[j] <= T) { srv[w][k] = c3[j]; ++k; }
    asm volatile("s_waitcnt lgkmcnt(0)" ::: "memory");
    unsigned long long s0 = srv[w][2 * l];
    unsigned long long s1 = srv[w][2 * l + 1];
    bitonic128(s0, s1, l);
    if (l < 24) {
      int2 o = make_int2((int)(unsigned int)s0, (int)(unsigned int)s1);
      *reinterpret_cast<int2*>(&idx_out[(size_t)bn * NB_KT + 2 * l]) = o;
    }
  } else {
#define POP(A)                                                \
  {                                                           \
    A[0] = A[1]; A[1] = A[2]; A[2] = A[3]; A[3] = A[4];       \
    A[4] = A[5]; A[5] = A[6]; A[6] = A[7]; A[7] = ~0ULL;      \
  }
    unsigned long long lm;
    {
      unsigned long long a = u64min(c0[0], c1[0]);
      unsigned long long b2 = u64min(c2[0], c3[0]);
      lm = u64min(a, b2);
    }
    unsigned int my_out = 0;
    for (int r = 0; r < NB_KT; ++r) {
      unsigned long long g = lm;
      DPP_MIN64(g, 0xB1)
      DPP_MIN64(g, 0x4E)
      DPP_MIN64(g, 0x141)
      DPP_MIN64(g, 0x140)
      {
        unsigned long long o = __shfl_xor(g, 16);
        if (o < g) g = o;
      }
      {
        unsigned long long o = __shfl_xor(g, 32);
        if (o < g) g = o;
      }
      if (l == r) my_out = (unsigned int)g;
      if (lm == g) {
        if (c0[0] == g) { POP(c0) }
        else if (c1[0] == g) { POP(c1) }
        else if (c2[0] == g) { POP(c2) }
        else { POP(c3) }
        unsigned long long a = u64min(c0[0], c1[0]);
        unsigned long long b2 = u64min(c2[0], c3[0]);
        lm = u64min(a, b2);
      }
    }
#undef POP
    if (l < NB_KT) idx_out[(size_t)bn * NB_KT + l] = (int)my_out;
  }
}

// ---------------------------------------------------------------------------
// main fused kernel v4: 4 waves/block, 4 points/wave (16 pts/block), grid 1024
// __launch_bounds__(256, 2): VGPR cap 256 (round-5's cap of 64 starved the
// fully-unrolled logits loop of load-pipelining registers -> latency-bound).
// lane layout: h_l = l>>4 (head), cg = l&15; lane owns channels
// {4cg..4cg+3, 64+4cg..64+4cg+3}. Neighbor rows direct global->reg.
// Logits reduce: transpose-butterfly — accumulate pp[j] per row unreduced,
// then 4 exchange steps (xor 1,2,4,8); lane cg ends with row cg's full dot.
// All LDS wave-private: no barriers.
// ---------------------------------------------------------------------------
__global__ __launch_bounds__(256, 2) void main_kernel(
    const float* __restrict__ pcd,
    const float* __restrict__ Wq, const float* __restrict__ bq,
    const float* __restrict__ bk,
    const float* __restrict__ Wv, const float* __restrict__ bv,
    const float* __restrict__ wkT,
    const int* __restrict__ nbr_idx,
    float* __restrict__ out) {
  __shared__ __align__(16) float self_lds[16][128];       // 8 KB
  __shared__ float q_lds[16][132];                        // 8.25 KB
  __shared__ float qbk_lds[16][12];                       // 768 B

  const int t = threadIdx.x;
  const int w = t >> 6, l = t & 63;
  const int h_l = l >> 4, cg = l & 15;
  const int ws = w * 4;                     // wave's slot base (4 points)
  const int pt_base = blockIdx.x * 16 + ws;
  const float* pcd_b = pcd + (size_t)((blockIdx.x * 16) >> 11) * NB_N * 128;

  // ---- stage self rows (wave-private slots) ----
#pragma unroll
  for (int p = 0; p < 4; ++p) {
    float2 s = reinterpret_cast<const float2*>(pcd + (size_t)(pt_base + p) * 128)[l];
    reinterpret_cast<float2*>(&self_lds[ws + p][0])[l] = s;
  }

  // ---- q,v matvec: lane owns output cols 2l, 2l+1 for 4 points ----
  float qa[4] = {0, 0, 0, 0}, qb[4] = {0, 0, 0, 0};
  float va[4] = {0, 0, 0, 0}, vb[4] = {0, 0, 0, 0};
#pragma unroll 8
  for (int c = 0; c < 128; ++c) {
    float2 wq = reinterpret_cast<const float2*>(Wq + c * 128)[l];
    float2 wv = reinterpret_cast<const float2*>(Wv + c * 128)[l];
#pragma unroll
    for (int p = 0; p < 4; ++p) {
      float x = self_lds[ws + p][c];
      qa[p] = fmaf(wq.x, x, qa[p]); qb[p] = fmaf(wq.y, x, qb[p]);
      va[p] = fmaf(wv.x, x, va[p]); vb[p] = fmaf(wv.y, x, vb[p]);
    }
  }
  {
    float2 bqv = reinterpret_cast<const float2*>(bq)[l];
    float2 bvv = reinterpret_cast<const float2*>(bv)[l];
#pragma unroll
    for (int p = 0; p < 4; ++p) {
      qa[p] += bqv.x; qb[p] += bqv.y; va[p] += bvv.x; vb[p] += bvv.y;
    }
  }
#pragma unroll
  for (int p = 0; p < 4; ++p) {
    q_lds[ws + p][h_l * 33 + 2 * cg] = qa[p];
    q_lds[ws + p][h_l * 33 + 2 * cg + 1] = qb[p];
  }
  // qbk[p][i][h] = q[h,:] . bk[i][h*32:...]  (48 lanes = 4 pts x 12)
  if (l < 48) {
    int p = l / 12, g = l % 12;
    int i = g >> 2, h = g & 3;
    const float* qp = &q_lds[ws + p][h * 33];
    const float* bkp = bk + i * 128 + h * 32;
    float s = 0.f;
#pragma unroll 8
    for (int d = 0; d < 32; ++d) s = fmaf(qp[d], bkp[d], s);
    qbk_lds[ws + p][g] = s;
  }

  int nidx[4];
#pragma unroll
  for (int p = 0; p < 4; ++p)
    nidx[p] = (l < 48) ? nbr_idx[(size_t)(pt_base + p) * NB_KT + l] : 0;

  float am[4] = {0, 0, 0, 0};

#pragma unroll
  for (int i = 0; i < 3; ++i) {
    // ---- u[p][t]: channel 4cg+t (t<4), 64+4cg+(t-4) (t>=4) ----
    float u[4][8];
#pragma unroll
    for (int p = 0; p < 4; ++p)
#pragma unroll
      for (int k = 0; k < 8; ++k) u[p][k] = 0.f;
    {
      const float* wrow = wkT + i * 16384 + (h_l * 32) * 128 + 4 * cg;
#pragma unroll 8
      for (int d = 0; d < 32; ++d) {
        float4 wa = *reinterpret_cast<const float4*>(wrow + d * 128);
        float4 wb = *reinterpret_cast<const float4*>(wrow + d * 128 + 64);
        float qv[4];
#pragma unroll
        for (int p = 0; p < 4; ++p) qv[p] = q_lds[ws + p][h_l * 33 + d];
#pragma unroll
        for (int p = 0; p < 4; ++p) {
          u[p][0] = fmaf(wa.x, qv[p], u[p][0]);
          u[p][1] = fmaf(wa.y, qv[p], u[p][1]);
          u[p][2] = fmaf(wa.z, qv[p], u[p][2]);
          u[p][3] = fmaf(wa.w, qv[p], u[p][3]);
          u[p][4] = fmaf(wb.x, qv[p], u[p][4]);
          u[p][5] = fmaf(wb.y, qv[p], u[p][5]);
          u[p][6] = fmaf(wb.z, qv[p], u[p][6]);
          u[p][7] = fmaf(wb.w, qv[p], u[p][7]);
        }
      }
    }
    // ---- base[p] = qbk[p][i][h_l] - sum_c self[c]*u[c] ----
    float base[4];
#pragma unroll
    for (int p = 0; p < 4; ++p) {
      const float4* sp = reinterpret_cast<const float4*>(&self_lds[ws + p][4 * cg]);
      float4 sA = sp[0];
      float4 sB = sp[16];   // +64 floats
      float sd;
      sd = sA.x * u[p][0];
      sd = fmaf(sA.y, u[p][1], sd);
      sd = fmaf(sA.z, u[p][2], sd);
      sd = fmaf(sA.w, u[p][3], sd);
      sd = fmaf(sB.x, u[p][4], sd);
      sd = fmaf(sB.y, u[p][5], sd);
      sd = fmaf(sB.z, u[p][6], sd);
      sd = fmaf(sB.w, u[p][7], sd);
      sd = sum16(sd);
      base[p] = qbk_lds[ws + p][i * 4 + h_l] - sd;
    }
    // ---- logits: 16 rows direct global->reg, butterfly transpose-reduce ----
#pragma unroll
    for (int p = 0; p < 4; ++p) {
      float pp[16];
#pragma unroll
      for (int j = 0; j < 16; ++j) {
        int nb = __builtin_amdgcn_readlane(nidx[p], i * 16 + j);  // SGPR base
        const float* rowp = pcd_b + (size_t)(unsigned)nb * 128 + 4 * cg;
        float4 nA = *reinterpret_cast<const float4*>(rowp);
        float4 nB = *reinterpret_cast<const float4*>(rowp + 64);
        float pd;
        pd = nA.x * u[p][0];
        pd = fmaf(nA.y, u[p][1], pd);
        pd = fmaf(nA.z, u[p][2], pd);
        pd = fmaf(nA.w, u[p][3], pd);
        pd = fmaf(nB.x, u[p][4], pd);
        pd = fmaf(nB.y, u[p][5], pd);
        pd = fmaf(nB.z, u[p][6], pd);
        pd = fmaf(nB.w, u[p][7], pd);
        pp[j] = pd;
      }
      // butterfly transpose-reduce over the 16-lane group:
      // step s: keep rows whose bit-s equals (cg&s); partner sends its
      // partial of MY row. After s=1,2,4,8: lane cg holds full dot of row cg.
      float b8[8];
#pragma unroll
      for (int j = 0; j < 8; ++j) {
        bool hi = (cg & 1) != 0;
        float mine = hi ? pp[2 * j + 1] : pp[2 * j];
        float sent = hi ? pp[2 * j] : pp[2 * j + 1];
        b8[j] = mine + DPP_F(sent, 0xB1);                 // xor 1
      }
      float b4[4];
#pragma unroll
      for (int j = 0; j < 4; ++j) {
        bool hi = (cg & 2) != 0;
        float mine = hi ? b8[2 * j + 1] : b8[2 * j];
        float sent = hi ? b8[2 * j] : b8[2 * j + 1];
        b4[j] = mine + DPP_F(sent, 0x4E);                 // xor 2
      }
      float b2[2];
#pragma unroll
      for (int j = 0; j < 2; ++j) {
        bool hi = (cg & 4) != 0;
        float mine = hi ? b4[2 * j + 1] : b4[2 * j];
        float sent = hi ? b4[2 * j] : b4[2 * j + 1];
        b2[j] = mine + SWZ_F(sent, 0x101F);               // xor 4
      }
      float b1;
      {
        bool hi = (cg & 8) != 0;
        float mine = hi ? b2[1] : b2[0];
        float sent = hi ? b2[0] : b2[1];
        b1 = mine + SWZ_F(sent, 0x201F);                  // xor 8
      }
      float myl = (b1 + base[p]) * INV_SQRT_D;
      // softmax over the 16 lanes of this head group (all-VALU DPP)
      float m = max16(myl);
      float e = expf(myl - m);
      float swl = e * myl;
      float se = sum16(e);
      swl = sum16(swl);
      am[p] += swl / se;
    }
  }

  // ---- epilogue: out[pt_p, 2l+{0,1}] = attn[h_l] * v ----
#pragma unroll
  for (int p = 0; p < 4; ++p) {
    float2 o = make_float2(am[p] * va[p], am[p] * vb[p]);
    reinterpret_cast<float2*>(out + (size_t)(pt_base + p) * 128)[l] = o;
  }
}

// ---------------------------------------------------------------------------
extern "C" void kernel_launch(void* const* d_in, const int* in_sizes, int n_in,
                              void* d_out, int out_size, void* d_ws, size_t ws_size,
                              hipStream_t stream) {
  const float* pcd   = (const float*)d_in[0];
  const float* coord = (const float*)d_in[1];
  // d_in[2] = K (scalar int, fixed 16 — hardcoded)
  const float* Wq = (const float*)d_in[3];
  const float* bq = (const float*)d_in[4];
  const float* Wk = (const float*)d_in[5];
  const float* bk = (const float*)d_in[6];
  const float* Wv = (const float*)d_in[7];
  const float* bv = (const float*)d_in[8];
  float* out = (float*)d_out;

  // workspace layout
  int*   idx_ws = (int*)d_ws;                                   // 16384*48*4 = 3,145,728 B
  float* sq_ws  = (float*)((char*)d_ws + 3145728);              // 65,536 B
  float* wkT_ws = (float*)((char*)d_ws + 3211264);              // 196,608 B

  prep_kernel<<<192, 256, 0, stream>>>(coord, Wk, sq_ws, wkT_ws);
  topk3_kernel<<<NB_B * NB_N / 4, 256, 0, stream>>>(coord, sq_ws, idx_ws);
  main_kernel<<<NB_B * NB_N / 16, 256, 0, stream>>>(pcd, Wq, bq, bk, Wv, bv,
                                                    wkT_ws, idx_ws, out);
}

// Round 7
// 246.871 us; speedup vs baseline: 1.1568x; 1.1568x over previous
//
#include <hip/hip_runtime.h>
#include <hip/hip_bf16.h>
#include <cstdint>
#include <cstddef>

#define NB_B 8
#define NB_N 2048
#define NB_C 128
#define NB_H 4
#define NB_D 32
#define NB_S1 3
#define NB_K 16
#define NB_KT 48
#define INV_SQRT_D 0.17677669529663688f

// ---- DPP reduce helpers: 16-lane group reduce, all-VALU (no DS ops) -------
#define DPP_F(x, ctrl) \
  __int_as_float(__builtin_amdgcn_update_dpp(0, __float_as_int(x), ctrl, 0xF, 0xF, true))

__device__ __forceinline__ float sum16(float x) {
  x += DPP_F(x, 0xB1);
  x += DPP_F(x, 0x4E);
  x += DPP_F(x, 0x141);
  x += DPP_F(x, 0x140);
  return x;
}
__device__ __forceinline__ float max16(float x) {
  x = fmaxf(x, DPP_F(x, 0xB1));
  x = fmaxf(x, DPP_F(x, 0x4E));
  x = fmaxf(x, DPP_F(x, 0x141));
  x = fmaxf(x, DPP_F(x, 0x140));
  return x;
}

__device__ __forceinline__ unsigned long long u64min(unsigned long long a,
                                                     unsigned long long b) {
  return a < b ? a : b;
}
__device__ __forceinline__ unsigned long long u64max(unsigned long long a,
                                                     unsigned long long b) {
  return a > b ? a : b;
}

// lane-xor exchange of a u64 across lanes. lx must be a power of 2 <= 32;
// after full unrolling the switch folds to the single matching path.
// xor1/xor2: DPP (VALU). xor4/8/16: ds_swizzle BitMode. xor32: shfl.
__device__ __forceinline__ unsigned int dpp32(unsigned int x, int sel) {
  if (sel == 0)
    return (unsigned int)__builtin_amdgcn_update_dpp(0, (int)x, 0xB1, 0xF, 0xF, true);
  return (unsigned int)__builtin_amdgcn_update_dpp(0, (int)x, 0x4E, 0xF, 0xF, true);
}
__device__ __forceinline__ unsigned long long lane_xor64(unsigned long long v, int lx) {
  if (lx == 32) return __shfl_xor(v, 32);
  unsigned int lo = (unsigned int)v, hi = (unsigned int)(v >> 32);
  switch (lx) {
    case 1:  lo = dpp32(lo, 0); hi = dpp32(hi, 0); break;
    case 2:  lo = dpp32(lo, 1); hi = dpp32(hi, 1); break;
    case 4:
      lo = (unsigned int)__builtin_amdgcn_ds_swizzle((int)lo, 0x101F);
      hi = (unsigned int)__builtin_amdgcn_ds_swizzle((int)hi, 0x101F);
      break;
    case 8:
      lo = (unsigned int)__builtin_amdgcn_ds_swizzle((int)lo, 0x201F);
      hi = (unsigned int)__builtin_amdgcn_ds_swizzle((int)hi, 0x201F);
      break;
    default:  // 16
      lo = (unsigned int)__builtin_amdgcn_ds_swizzle((int)lo, 0x401F);
      hi = (unsigned int)__builtin_amdgcn_ds_swizzle((int)hi, 0x401F);
      break;
  }
  return ((unsigned long long)hi << 32) | lo;
}

// Canonical bitonic sort of 128 u64 across a wave (2 elements/lane,
// global index = 2*lane + r), ascending. 28 steps: 7 in-lane, 21 cross-lane.
__device__ __forceinline__ void bitonic128(unsigned long long& v0,
                                           unsigned long long& v1, int L) {
#pragma unroll
  for (int k = 2; k <= 128; k <<= 1) {
#pragma unroll
    for (int j = k >> 1; j > 0; j >>= 1) {
      bool up = ((L & (k >> 1)) == 0);
      if (j == 1) {
        unsigned long long lo = u64min(v0, v1), hi = u64max(v0, v1);
        v0 = up ? lo : hi;
        v1 = up ? hi : lo;
      } else {
        int lx = j >> 1;
        unsigned long long o0 = lane_xor64(v0, lx);
        unsigned long long o1 = lane_xor64(v1, lx);
        bool keepmin = (((L & lx) == 0) == up);
        v0 = keepmin ? u64min(v0, o0) : u64max(v0, o0);
        v1 = keepmin ? u64min(v1, o1) : u64max(v1, o1);
      }
    }
  }
}

// ---------------------------------------------------------------------------
// prep: sq[b,n] = |coord|^2  and  WkT[i][col][c] = Wk[i][c][col]
// ---------------------------------------------------------------------------
__global__ __launch_bounds__(256) void prep_kernel(const float* __restrict__ coord,
                                                   const float* __restrict__ Wk,
                                                   float* __restrict__ sq,
                                                   float* __restrict__ wkT) {
  int tid = blockIdx.x * 256 + threadIdx.x;
  if (tid < NB_B * NB_N) {
    float x = coord[tid * 3 + 0], y = coord[tid * 3 + 1], z = coord[tid * 3 + 2];
    sq[tid] = x * x + y * y + z * z;
  }
  if (tid < NB_S1 * NB_C * NB_C) {
    int i = tid >> 14;          // / 16384
    int rem = tid & 16383;
    int col = rem >> 7, c = rem & 127;
    wkT[tid] = Wk[i * 16384 + c * 128 + col];
  }
}

// ---------------------------------------------------------------------------
// topk4: ONE WAVE per point. 32 u32 dist-keys/lane in fixed slots
// (slot-implicit candidate index m = it*64 + l -> u64 key built on the fly:
// (dk<<32)|m, identical key values to topk3 => identical exact ordering).
// T = 48th smallest of per-lane top-2 samples (bitonic128); fused
// ballot/mbcnt count+compact to LDS; bitonic128 over survivors; exact
// popped-bitmask serial-extraction fallback if survivors > 128.
// Target: VGPR <= 64 -> 8 waves/SIMD.
// ---------------------------------------------------------------------------
__global__ __launch_bounds__(256) void topk4_kernel(const float* __restrict__ coord,
                                                    const float* __restrict__ sq,
                                                    int* __restrict__ idx_out) {
  __shared__ unsigned long long srv[4][128];   // per-wave survivor buffer (4 KB)
  const int t = threadIdx.x;
  const int w = t >> 6, l = t & 63;
  const int bn = blockIdx.x * 4 + w;          // one wave per point
  const int b = bn >> 11, n = bn & 2047;
  const float* cb = coord + (size_t)b * NB_N * 3;
  const float* sqb = sq + b * NB_N;

  const float cx = cb[n * 3 + 0], cy = cb[n * 3 + 1], cz = cb[n * 3 + 2];
  const float sqn = sqb[n];

  unsigned int dk[32];
#pragma unroll
  for (int it = 0; it < 32; ++it) {
    int m = it * 64 + l;
    float mx = cb[m * 3 + 0], my = cb[m * 3 + 1], mz = cb[m * 3 + 2];
    float d = sqn + sqb[m] - 2.f * (cx * mx + cy * my + cz * mz);
    unsigned int db = __float_as_uint(d);
    dk[it] = (db & 0x80000000u) ? ~db : (db | 0x80000000u);
  }

#define KEY(IT) ((((unsigned long long)dk[(IT)]) << 32) | (unsigned int)((IT) * 64 + l))

  // ---- per-lane two smallest (streaming scan) ----
  unsigned long long m1 = ~0ULL, m2 = ~0ULL;
#pragma unroll
  for (int it = 0; it < 32; ++it) {
    unsigned long long k = KEY(it);
    if (k < m1) { m2 = m1; m1 = k; }
    else if (k < m2) { m2 = k; }
  }

  // ---- T = 48th smallest of the 128 samples ----
  unsigned long long v0 = m1, v1 = m2;
  bitonic128(v0, v1, l);
  const unsigned long long T = __shfl(v1, 23);   // global element #47

  // ---- pad survivor buffer, then fused count+compact (ballot + mbcnt) ----
  srv[w][l] = ~0ULL;
  srv[w][l + 64] = ~0ULL;
  int base = 0;
#pragma unroll
  for (int it = 0; it < 32; ++it) {
    unsigned long long k = KEY(it);
    bool pred = (k <= T);
    unsigned long long mask = __ballot(pred);
    int my = base +
             (int)__builtin_amdgcn_mbcnt_hi(
                 (unsigned int)(mask >> 32),
                 __builtin_amdgcn_mbcnt_lo((unsigned int)mask, 0u));
    if (pred && my < 128) srv[w][my] = k;
    base += (int)__popcll(mask);
  }

  if (base <= 128) {
    asm volatile("s_waitcnt lgkmcnt(0)" ::: "memory");
    unsigned long long s0 = srv[w][2 * l];
    unsigned long long s1 = srv[w][2 * l + 1];
    bitonic128(s0, s1, l);
    if (l < 24) {
      int2 o = make_int2((int)(unsigned int)s0, (int)(unsigned int)s1);
      *reinterpret_cast<int2*>(&idx_out[(size_t)bn * NB_KT + 2 * l]) = o;
    }
  } else {
    // ---- exact fallback: serial extraction with popped-slot bitmask ----
    unsigned int popped = 0;
    unsigned int my_out = 0;
    for (int r = 0; r < NB_KT; ++r) {
      unsigned long long lm = ~0ULL;
      int lslot = 0;
#pragma unroll
      for (int it = 0; it < 32; ++it) {
        unsigned long long k = KEY(it);
        bool ok = ((popped >> it) & 1u) == 0u && k < lm;
        if (ok) { lm = k; lslot = it; }
      }
      unsigned long long g = lm;
#pragma unroll
      for (int lx = 1; lx <= 32; lx <<= 1) {
        unsigned long long o = lane_xor64(g, lx);
        if (o < g) g = o;
      }
      if (l == r) my_out = (unsigned int)g;
      if (lm == g) popped |= (1u << lslot);
    }
    if (l < NB_KT) idx_out[(size_t)bn * NB_KT + l] = (int)my_out;
  }
#undef KEY
}

// ---------------------------------------------------------------------------
// main fused kernel v5: 4 waves/block, 4 points/wave (16 pts/block), grid 1024
// lane layout: h_l = l>>4 (head), cg = l&15; lane owns channels
// {4cg..4cg+3, 64+4cg..64+4cg+3}. Neighbor rows: direct global->reg with an
// EXPLICIT 4-deep rolling register stage (compiler won't pipeline on its own:
// VGPR stayed 68 across rounds 4-6 -> just-in-time loads, 25-31% VALUBusy).
// Per-row reduce: sum16 (round-4 proven; butterfly regressed in round 6).
// All LDS wave-private: no barriers.
// ---------------------------------------------------------------------------
__global__ __launch_bounds__(256) void main_kernel(
    const float* __restrict__ pcd,
    const float* __restrict__ Wq, const float* __restrict__ bq,
    const float* __restrict__ bk,
    const float* __restrict__ Wv, const float* __restrict__ bv,
    const float* __restrict__ wkT,
    const int* __restrict__ nbr_idx,
    float* __restrict__ out) {
  __shared__ __align__(16) float self_lds[16][128];       // 8 KB
  __shared__ __align__(8) float q_lds[16][136];           // 8.5 KB (4 heads x 34)
  __shared__ float qbk_lds[16][12];                       // 768 B

  const int t = threadIdx.x;
  const int w = t >> 6, l = t & 63;
  const int h_l = l >> 4, cg = l & 15;
  const int ws = w * 4;                     // wave's slot base (4 points)
  const int pt_base = blockIdx.x * 16 + ws;
  const float* pcd_b = pcd + (size_t)((blockIdx.x * 16) >> 11) * NB_N * 128;

  // ---- stage self rows (wave-private slots) ----
#pragma unroll
  for (int p = 0; p < 4; ++p) {
    float2 s = reinterpret_cast<const float2*>(pcd + (size_t)(pt_base + p) * 128)[l];
    reinterpret_cast<float2*>(&self_lds[ws + p][0])[l] = s;
  }

  // ---- q,v matvec: lane owns output cols 2l, 2l+1; c-pairs with b64 x ----
  float qa[4] = {0, 0, 0, 0}, qb[4] = {0, 0, 0, 0};
  float va[4] = {0, 0, 0, 0}, vb[4] = {0, 0, 0, 0};
#pragma unroll 4
  for (int c = 0; c < 128; c += 2) {
    float2 wq0 = reinterpret_cast<const float2*>(Wq + c * 128)[l];
    float2 wv0 = reinterpret_cast<const float2*>(Wv + c * 128)[l];
    float2 wq1 = reinterpret_cast<const float2*>(Wq + (c + 1) * 128)[l];
    float2 wv1 = reinterpret_cast<const float2*>(Wv + (c + 1) * 128)[l];
#pragma unroll
    for (int p = 0; p < 4; ++p) {
      float2 x2 = *reinterpret_cast<const float2*>(&self_lds[ws + p][c]);
      qa[p] = fmaf(wq0.x, x2.x, qa[p]); qb[p] = fmaf(wq0.y, x2.x, qb[p]);
      va[p] = fmaf(wv0.x, x2.x, va[p]); vb[p] = fmaf(wv0.y, x2.x, vb[p]);
      qa[p] = fmaf(wq1.x, x2.y, qa[p]); qb[p] = fmaf(wq1.y, x2.y, qb[p]);
      va[p] = fmaf(wv1.x, x2.y, va[p]); vb[p] = fmaf(wv1.y, x2.y, vb[p]);
    }
  }
  {
    float2 bqv = reinterpret_cast<const float2*>(bq)[l];
    float2 bvv = reinterpret_cast<const float2*>(bv)[l];
#pragma unroll
    for (int p = 0; p < 4; ++p) {
      qa[p] += bqv.x; qb[p] += bqv.y; va[p] += bvv.x; vb[p] += bvv.y;
    }
  }
#pragma unroll
  for (int p = 0; p < 4; ++p) {
    *reinterpret_cast<float2*>(&q_lds[ws + p][h_l * 34 + 2 * cg]) =
        make_float2(qa[p], qb[p]);
  }
  // qbk[p][i][h] = q[h,:] . bk[i][h*32:...]  (48 lanes = 4 pts x 12)
  if (l < 48) {
    int p = l / 12, g = l % 12;
    int i = g >> 2, h = g & 3;
    const float* qp = &q_lds[ws + p][h * 34];
    const float* bkp = bk + i * 128 + h * 32;
    float s = 0.f;
#pragma unroll 8
    for (int d = 0; d < 32; ++d) s = fmaf(qp[d], bkp[d], s);
    qbk_lds[ws + p][g] = s;
  }

  int nidx[4];
#pragma unroll
  for (int p = 0; p < 4; ++p)
    nidx[p] = (l < 48) ? nbr_idx[(size_t)(pt_base + p) * NB_KT + l] : 0;

  float am[4] = {0, 0, 0, 0};

#pragma unroll
  for (int i = 0; i < 3; ++i) {
    // ---- u[p][t]: channel 4cg+t (t<4), 64+4cg+(t-4) (t>=4); d-pairs ----
    float u[4][8];
#pragma unroll
    for (int p = 0; p < 4; ++p)
#pragma unroll
      for (int k = 0; k < 8; ++k) u[p][k] = 0.f;
    {
      const float* wrow = wkT + i * 16384 + (h_l * 32) * 128 + 4 * cg;
#pragma unroll 4
      for (int d = 0; d < 32; d += 2) {
        float4 wa0 = *reinterpret_cast<const float4*>(wrow + d * 128);
        float4 wb0 = *reinterpret_cast<const float4*>(wrow + d * 128 + 64);
        float4 wa1 = *reinterpret_cast<const float4*>(wrow + (d + 1) * 128);
        float4 wb1 = *reinterpret_cast<const float4*>(wrow + (d + 1) * 128 + 64);
#pragma unroll
        for (int p = 0; p < 4; ++p) {
          float2 qv2 = *reinterpret_cast<const float2*>(&q_lds[ws + p][h_l * 34 + d]);
          u[p][0] = fmaf(wa0.x, qv2.x, u[p][0]);
          u[p][1] = fmaf(wa0.y, qv2.x, u[p][1]);
          u[p][2] = fmaf(wa0.z, qv2.x, u[p][2]);
          u[p][3] = fmaf(wa0.w, qv2.x, u[p][3]);
          u[p][4] = fmaf(wb0.x, qv2.x, u[p][4]);
          u[p][5] = fmaf(wb0.y, qv2.x, u[p][5]);
          u[p][6] = fmaf(wb0.z, qv2.x, u[p][6]);
          u[p][7] = fmaf(wb0.w, qv2.x, u[p][7]);
          u[p][0] = fmaf(wa1.x, qv2.y, u[p][0]);
          u[p][1] = fmaf(wa1.y, qv2.y, u[p][1]);
          u[p][2] = fmaf(wa1.z, qv2.y, u[p][2]);
          u[p][3] = fmaf(wa1.w, qv2.y, u[p][3]);
          u[p][4] = fmaf(wb1.x, qv2.y, u[p][4]);
          u[p][5] = fmaf(wb1.y, qv2.y, u[p][5]);
          u[p][6] = fmaf(wb1.z, qv2.y, u[p][6]);
          u[p][7] = fmaf(wb1.w, qv2.y, u[p][7]);
        }
      }
    }
    // ---- base[p] = qbk[p][i][h_l] - sum_c self[c]*u[c] ----
    float base[4];
#pragma unroll
    for (int p = 0; p < 4; ++p) {
      const float4* sp = reinterpret_cast<const float4*>(&self_lds[ws + p][4 * cg]);
      float4 sA = sp[0];
      float4 sB = sp[16];   // +64 floats
      float sd;
      sd = sA.x * u[p][0];
      sd = fmaf(sA.y, u[p][1], sd);
      sd = fmaf(sA.z, u[p][2], sd);
      sd = fmaf(sA.w, u[p][3], sd);
      sd = fmaf(sB.x, u[p][4], sd);
      sd = fmaf(sB.y, u[p][5], sd);
      sd = fmaf(sB.z, u[p][6], sd);
      sd = fmaf(sB.w, u[p][7], sd);
      sd = sum16(sd);
      base[p] = qbk_lds[ws + p][i * 4 + h_l] - sd;
    }
    // ---- logits: 16 rows, explicit 4-deep rolling register stage ----
#pragma unroll
    for (int p = 0; p < 4; ++p) {
      float4 sA[4], sB[4];
#define LOADROW(J, SLOT)                                                     \
  {                                                                          \
    int nb_ = __builtin_amdgcn_readlane(nidx[p], i * 16 + (J));              \
    const float* rp_ = pcd_b + (size_t)(unsigned)nb_ * 128 + 4 * cg;         \
    sA[(SLOT)] = *reinterpret_cast<const float4*>(rp_);                      \
    sB[(SLOT)] = *reinterpret_cast<const float4*>(rp_ + 64);                 \
  }
      LOADROW(0, 0) LOADROW(1, 1) LOADROW(2, 2) LOADROW(3, 3)
      float myl = 0.f;
#pragma unroll
      for (int jg = 0; jg < 4; ++jg) {
#pragma unroll
        for (int js = 0; js < 4; ++js) {
          const int j = jg * 4 + js;
          float4 nA = sA[js], nB = sB[js];
          if (jg < 3) LOADROW(j + 4, js)   // refill slot for group jg+1
          float pd;
          pd = nA.x * u[p][0];
          pd = fmaf(nA.y, u[p][1], pd);
          pd = fmaf(nA.z, u[p][2], pd);
          pd = fmaf(nA.w, u[p][3], pd);
          pd = fmaf(nB.x, u[p][4], pd);
          pd = fmaf(nB.y, u[p][5], pd);
          pd = fmaf(nB.z, u[p][6], pd);
          pd = fmaf(nB.w, u[p][7], pd);
          pd = sum16(pd);
          float lg = (pd + base[p]) * INV_SQRT_D;
          if (cg == j) myl = lg;
        }
      }
#undef LOADROW
      // softmax over the 16 lanes of this head group (all-VALU DPP)
      float m = max16(myl);
      float e = expf(myl - m);
      float swl = e * myl;
      float se = sum16(e);
      swl = sum16(swl);
      am[p] += swl / se;
    }
  }

  // ---- epilogue: out[pt_p, 2l+{0,1}] = attn[h_l] * v ----
#pragma unroll
  for (int p = 0; p < 4; ++p) {
    float2 o = make_float2(am[p] * va[p], am[p] * vb[p]);
    reinterpret_cast<float2*>(out + (size_t)(pt_base + p) * 128)[l] = o;
  }
}

// ---------------------------------------------------------------------------
extern "C" void kernel_launch(void* const* d_in, const int* in_sizes, int n_in,
                              void* d_out, int out_size, void* d_ws, size_t ws_size,
                              hipStream_t stream) {
  const float* pcd   = (const float*)d_in[0];
  const float* coord = (const float*)d_in[1];
  // d_in[2] = K (scalar int, fixed 16 — hardcoded)
  const float* Wq = (const float*)d_in[3];
  const float* bq = (const float*)d_in[4];
  const float* Wk = (const float*)d_in[5];
  const float* bk = (const float*)d_in[6];
  const float* Wv = (const float*)d_in[7];
  const float* bv = (const float*)d_in[8];
  float* out = (float*)d_out;

  // workspace layout
  int*   idx_ws = (int*)d_ws;                                   // 16384*48*4 = 3,145,728 B
  float* sq_ws  = (float*)((char*)d_ws + 3145728);              // 65,536 B
  float* wkT_ws = (float*)((char*)d_ws + 3211264);              // 196,608 B

  prep_kernel<<<192, 256, 0, stream>>>(coord, Wk, sq_ws, wkT_ws);
  topk4_kernel<<<NB_B * NB_N / 4, 256, 0, stream>>>(coord, sq_ws, idx_ws);
  main_kernel<<<NB_B * NB_N / 16, 256, 0, stream>>>(pcd, Wq, bq, bk, Wv, bv,
                                                    wkT_ws, idx_ws, out);
}

// Round 9
// 246.278 us; speedup vs baseline: 1.1595x; 1.0024x over previous
//
#include <hip/hip_runtime.h>
#include <hip/hip_bf16.h>
#include <cstdint>
#include <cstddef>

#define NB_B 8
#define NB_N 2048
#define NB_C 128
#define NB_H 4
#define NB_D 32
#define NB_S1 3
#define NB_K 16
#define NB_KT 48
#define INV_SQRT_D 0.17677669529663688f

// ---- DPP reduce helpers: 16-lane group reduce, all-VALU (no DS ops) -------
#define DPP_F(x, ctrl) \
  __int_as_float(__builtin_amdgcn_update_dpp(0, __float_as_int(x), ctrl, 0xF, 0xF, true))

__device__ __forceinline__ float sum16(float x) {
  x += DPP_F(x, 0xB1);
  x += DPP_F(x, 0x4E);
  x += DPP_F(x, 0x141);
  x += DPP_F(x, 0x140);
  return x;
}
__device__ __forceinline__ float max16(float x) {
  x = fmaxf(x, DPP_F(x, 0xB1));
  x = fmaxf(x, DPP_F(x, 0x4E));
  x = fmaxf(x, DPP_F(x, 0x141));
  x = fmaxf(x, DPP_F(x, 0x140));
  return x;
}

__device__ __forceinline__ unsigned long long u64min(unsigned long long a,
                                                     unsigned long long b) {
  return a < b ? a : b;
}
__device__ __forceinline__ unsigned long long u64max(unsigned long long a,
                                                     unsigned long long b) {
  return a > b ? a : b;
}

// lane-xor exchange of a u64 across lanes (power-of-2 lx <= 32).
// xor1/xor2: DPP (VALU). xor4/8/16: ds_swizzle BitMode. xor32: shfl.
__device__ __forceinline__ unsigned int dpp32(unsigned int x, int sel) {
  if (sel == 0)
    return (unsigned int)__builtin_amdgcn_update_dpp(0, (int)x, 0xB1, 0xF, 0xF, true);
  return (unsigned int)__builtin_amdgcn_update_dpp(0, (int)x, 0x4E, 0xF, 0xF, true);
}
__device__ __forceinline__ unsigned long long lane_xor64(unsigned long long v, int lx) {
  if (lx == 32) return __shfl_xor(v, 32);
  unsigned int lo = (unsigned int)v, hi = (unsigned int)(v >> 32);
  switch (lx) {
    case 1:  lo = dpp32(lo, 0); hi = dpp32(hi, 0); break;
    case 2:  lo = dpp32(lo, 1); hi = dpp32(hi, 1); break;
    case 4:
      lo = (unsigned int)__builtin_amdgcn_ds_swizzle((int)lo, 0x101F);
      hi = (unsigned int)__builtin_amdgcn_ds_swizzle((int)hi, 0x101F);
      break;
    case 8:
      lo = (unsigned int)__builtin_amdgcn_ds_swizzle((int)lo, 0x201F);
      hi = (unsigned int)__builtin_amdgcn_ds_swizzle((int)hi, 0x201F);
      break;
    default:  // 16
      lo = (unsigned int)__builtin_amdgcn_ds_swizzle((int)lo, 0x401F);
      hi = (unsigned int)__builtin_amdgcn_ds_swizzle((int)hi, 0x401F);
      break;
  }
  return ((unsigned long long)hi << 32) | lo;
}

// Bitonic sort of 128 u64 across a wave (2/lane, global index 2l+r), asc.
__device__ __forceinline__ void bitonic128(unsigned long long& v0,
                                           unsigned long long& v1, int L) {
#pragma unroll
  for (int k = 2; k <= 128; k <<= 1) {
#pragma unroll
    for (int j = k >> 1; j > 0; j >>= 1) {
      bool up = ((L & (k >> 1)) == 0);
      if (j == 1) {
        unsigned long long lo = u64min(v0, v1), hi = u64max(v0, v1);
        v0 = up ? lo : hi;
        v1 = up ? hi : lo;
      } else {
        int lx = j >> 1;
        unsigned long long o0 = lane_xor64(v0, lx);
        unsigned long long o1 = lane_xor64(v1, lx);
        bool keepmin = (((L & lx) == 0) == up);
        v0 = keepmin ? u64min(v0, o0) : u64max(v0, o0);
        v1 = keepmin ? u64min(v1, o1) : u64max(v1, o1);
      }
    }
  }
}

// Bitonic sort of 64 u64 across a wave (1/lane), ascending. 21 steps.
__device__ __forceinline__ unsigned long long bitonic64(unsigned long long v, int l) {
#pragma unroll
  for (int k = 2; k <= 64; k <<= 1) {
#pragma unroll
    for (int j = k >> 1; j > 0; j >>= 1) {
      unsigned long long o = lane_xor64(v, j);
      bool up = ((l & k) == 0);
      bool keepmin = (((l & j) == 0) == up);
      v = keepmin ? u64min(v, o) : u64max(v, o);
    }
  }
  return v;
}

// ---------------------------------------------------------------------------
// prep: sq[b,n] = |coord|^2  and  WkT[i][col][c] = Wk[i][c][col]
// ---------------------------------------------------------------------------
__global__ __launch_bounds__(256) void prep_kernel(const float* __restrict__ coord,
                                                   const float* __restrict__ Wk,
                                                   float* __restrict__ sq,
                                                   float* __restrict__ wkT) {
  int tid = blockIdx.x * 256 + threadIdx.x;
  if (tid < NB_B * NB_N) {
    float x = coord[tid * 3 + 0], y = coord[tid * 3 + 1], z = coord[tid * 3 + 2];
    sq[tid] = x * x + y * y + z * z;
  }
  if (tid < NB_S1 * NB_C * NB_C) {
    int i = tid >> 14;          // / 16384
    int rem = tid & 16383;
    int col = rem >> 7, c = rem & 127;
    wkT[tid] = Wk[i * 16384 + c * 128 + col];
  }
}

// deterministic dist-key: identical __fmaf_rn sequence at every call site ->
// bit-identical recompute across passes (required for the T-bound proof).
__device__ __forceinline__ unsigned int dist_key(const float* __restrict__ cb,
                                                 const float* __restrict__ sqb,
                                                 float cx, float cy, float cz,
                                                 float sqn, int m) {
  float mx = cb[m * 3 + 0], my = cb[m * 3 + 1], mz = cb[m * 3 + 2];
  float dot = __fmaf_rn(cz, mz, __fmaf_rn(cy, my, cx * mx));
  float d = sqn + sqb[m] - 2.f * dot;
  unsigned int db = __float_as_uint(d);
  return (db & 0x80000000u) ? ~db : (db | 0x80000000u);
}

// ---------------------------------------------------------------------------
// topk5: ONE WAVE per point, two-pass (no dk[32] array -> low VGPR).
// Pass 1: per-lane two smallest keys (m = it*64+l). T = 48th smallest of the
// 128 samples (bitonic128) — provable upper bound on the 48th global key.
// Pass 2: recompute keys, fused ballot/mbcnt compact of all keys <= T to LDS.
// Sort survivors: bitonic64 (M<=64, ~95%) / bitonic128 (M<=128) / exact
// serial-extraction fallback (recompute, popped-bitmask) otherwise.
// Key = (monotonic_u32(dist)<<32)|idx  => exact (dist, idx) ascending order.
// ---------------------------------------------------------------------------
__global__ __launch_bounds__(256) void topk5_kernel(const float* __restrict__ coord,
                                                    const float* __restrict__ sq,
                                                    int* __restrict__ idx_out) {
  __shared__ unsigned long long srv[4][128];   // per-wave survivor buffer (4 KB)
  const int t = threadIdx.x;
  const int w = t >> 6, l = t & 63;
  const int bn = blockIdx.x * 4 + w;          // one wave per point
  const int b = bn >> 11, n = bn & 2047;
  const float* cb = coord + (size_t)b * NB_N * 3;
  const float* sqb = sq + b * NB_N;

  const float cx = cb[n * 3 + 0], cy = cb[n * 3 + 1], cz = cb[n * 3 + 2];
  const float sqn = sqb[n];

#define KEY(IT)                                                               \
  ((((unsigned long long)dist_key(cb, sqb, cx, cy, cz, sqn, (IT) * 64 + l))   \
    << 32) |                                                                  \
   (unsigned int)((IT) * 64 + l))

  // ---- pass 1: per-lane two smallest ----
  unsigned long long m1 = ~0ULL, m2 = ~0ULL;
#pragma unroll 8
  for (int it = 0; it < 32; ++it) {
    unsigned long long k = KEY(it);
    if (k < m1) { m2 = m1; m1 = k; }
    else if (k < m2) { m2 = k; }
  }

  // ---- T = 48th smallest of the 128 samples ----
  unsigned long long v0 = m1, v1 = m2;
  bitonic128(v0, v1, l);
  const unsigned long long T = __shfl(v1, 23);   // global element #47

  // ---- pass 2: pad, recompute, fused count+compact (ballot + mbcnt) ----
  srv[w][l] = ~0ULL;
  srv[w][l + 64] = ~0ULL;
  int M = 0;
#pragma unroll 8
  for (int it = 0; it < 32; ++it) {
    unsigned long long k = KEY(it);
    bool pred = (k <= T);
    unsigned long long mask = __ballot(pred);
    int my = M +
             (int)__builtin_amdgcn_mbcnt_hi(
                 (unsigned int)(mask >> 32),
                 __builtin_amdgcn_mbcnt_lo((unsigned int)mask, 0u));
    if (pred && my < 128) srv[w][my] = k;
    M += (int)__popcll(mask);
  }

  if (M <= 64) {
    asm volatile("s_waitcnt lgkmcnt(0)" ::: "memory");
    unsigned long long s = bitonic64(srv[w][l], l);
    if (l < NB_KT) idx_out[(size_t)bn * NB_KT + l] = (int)(unsigned int)s;
  } else if (M <= 128) {
    asm volatile("s_waitcnt lgkmcnt(0)" ::: "memory");
    unsigned long long s0 = srv[w][2 * l];
    unsigned long long s1 = srv[w][2 * l + 1];
    bitonic128(s0, s1, l);
    if (l < 24) {
      int2 o = make_int2((int)(unsigned int)s0, (int)(unsigned int)s1);
      *reinterpret_cast<int2*>(&idx_out[(size_t)bn * NB_KT + 2 * l]) = o;
    }
  } else {
    // ---- exact fallback (pathological): serial extraction, recompute ----
    unsigned int popped = 0;
    unsigned int my_out = 0;
    for (int r = 0; r < NB_KT; ++r) {
      unsigned long long lm = ~0ULL;
      int lslot = 0;
      for (int it = 0; it < 32; ++it) {
        unsigned long long k = KEY(it);
        bool ok = ((popped >> it) & 1u) == 0u && k < lm;
        if (ok) { lm = k; lslot = it; }
      }
      unsigned long long g = lm;
#pragma unroll
      for (int lx = 1; lx <= 32; lx <<= 1) {
        unsigned long long o = lane_xor64(g, lx);
        if (o < g) g = o;
      }
      if (l == r) my_out = (unsigned int)g;
      if (lm == g) popped |= (1u << lslot);
    }
    if (l < NB_KT) idx_out[(size_t)bn * NB_KT + l] = (int)my_out;
  }
#undef KEY
}

// ---------------------------------------------------------------------------
// main fused kernel v6: 2 waves/block (128 threads), 4 points/wave, grid 2048.
// Round-7 showed VGPR=80 permits 6 waves/SIMD but 256-thread blocks at grid
// 1024 capped us at 4 blocks/CU (occupancy 26.8%). 128-thread blocks give
// 16 blocks/CU -> VGPR-capped ~24 waves/CU. Per-wave code identical to r7:
// rolling 4-deep register stage for neighbor rows, sum16 DPP reduces,
// wave-private LDS, no barriers.
// ---------------------------------------------------------------------------
__global__ __launch_bounds__(128) void main_kernel(
    const float* __restrict__ pcd,
    const float* __restrict__ Wq, const float* __restrict__ bq,
    const float* __restrict__ bk,
    const float* __restrict__ Wv, const float* __restrict__ bv,
    const float* __restrict__ wkT,
    const int* __restrict__ nbr_idx,
    float* __restrict__ out) {
  __shared__ __align__(16) float self_lds[8][128];        // 4 KB
  __shared__ __align__(8) float q_lds[8][136];            // 4.25 KB (4 heads x 34)
  __shared__ float qbk_lds[8][12];                        // 384 B

  const int t = threadIdx.x;
  const int w = t >> 6, l = t & 63;
  const int h_l = l >> 4, cg = l & 15;
  const int ws = w * 4;                     // wave's slot base (4 points)
  const int pt_base = blockIdx.x * 8 + ws;
  const float* pcd_b = pcd + (size_t)((blockIdx.x * 8) >> 11) * NB_N * 128;

  // ---- stage self rows (wave-private slots) ----
#pragma unroll
  for (int p = 0; p < 4; ++p) {
    float2 s = reinterpret_cast<const float2*>(pcd + (size_t)(pt_base + p) * 128)[l];
    reinterpret_cast<float2*>(&self_lds[ws + p][0])[l] = s;
  }

  // ---- q,v matvec: lane owns output cols 2l, 2l+1; c-pairs with b64 x ----
  float qa[4] = {0, 0, 0, 0}, qb[4] = {0, 0, 0, 0};
  float va[4] = {0, 0, 0, 0}, vb[4] = {0, 0, 0, 0};
#pragma unroll 4
  for (int c = 0; c < 128; c += 2) {
    float2 wq0 = reinterpret_cast<const float2*>(Wq + c * 128)[l];
    float2 wv0 = reinterpret_cast<const float2*>(Wv + c * 128)[l];
    float2 wq1 = reinterpret_cast<const float2*>(Wq + (c + 1) * 128)[l];
    float2 wv1 = reinterpret_cast<const float2*>(Wv + (c + 1) * 128)[l];
#pragma unroll
    for (int p = 0; p < 4; ++p) {
      float2 x2 = *reinterpret_cast<const float2*>(&self_lds[ws + p][c]);
      qa[p] = fmaf(wq0.x, x2.x, qa[p]); qb[p] = fmaf(wq0.y, x2.x, qb[p]);
      va[p] = fmaf(wv0.x, x2.x, va[p]); vb[p] = fmaf(wv0.y, x2.x, vb[p]);
      qa[p] = fmaf(wq1.x, x2.y, qa[p]); qb[p] = fmaf(wq1.y, x2.y, qb[p]);
      va[p] = fmaf(wv1.x, x2.y, va[p]); vb[p] = fmaf(wv1.y, x2.y, vb[p]);
    }
  }
  {
    float2 bqv = reinterpret_cast<const float2*>(bq)[l];
    float2 bvv = reinterpret_cast<const float2*>(bv)[l];
#pragma unroll
    for (int p = 0; p < 4; ++p) {
      qa[p] += bqv.x; qb[p] += bqv.y; va[p] += bvv.x; vb[p] += bvv.y;
    }
  }
#pragma unroll
  for (int p = 0; p < 4; ++p) {
    *reinterpret_cast<float2*>(&q_lds[ws + p][h_l * 34 + 2 * cg]) =
        make_float2(qa[p], qb[p]);
  }
  // qbk[p][i][h] = q[h,:] . bk[i][h*32:...]  (48 lanes = 4 pts x 12)
  if (l < 48) {
    int p = l / 12, g = l % 12;
    int i = g >> 2, h = g & 3;
    const float* qp = &q_lds[ws + p][h * 34];
    const float* bkp = bk + i * 128 + h * 32;
    float s = 0.f;
#pragma unroll 8
    for (int d = 0; d < 32; ++d) s = fmaf(qp[d], bkp[d], s);
    qbk_lds[ws + p][g] = s;
  }

  int nidx[4];
#pragma unroll
  for (int p = 0; p < 4; ++p)
    nidx[p] = (l < 48) ? nbr_idx[(size_t)(pt_base + p) * NB_KT + l] : 0;

  float am[4] = {0, 0, 0, 0};

#pragma unroll
  for (int i = 0; i < 3; ++i) {
    // ---- u[p][t]: channel 4cg+t (t<4), 64+4cg+(t-4) (t>=4); d-pairs ----
    float u[4][8];
#pragma unroll
    for (int p = 0; p < 4; ++p)
#pragma unroll
      for (int k = 0; k < 8; ++k) u[p][k] = 0.f;
    {
      const float* wrow = wkT + i * 16384 + (h_l * 32) * 128 + 4 * cg;
#pragma unroll 4
      for (int d = 0; d < 32; d += 2) {
        float4 wa0 = *reinterpret_cast<const float4*>(wrow + d * 128);
        float4 wb0 = *reinterpret_cast<const float4*>(wrow + d * 128 + 64);
        float4 wa1 = *reinterpret_cast<const float4*>(wrow + (d + 1) * 128);
        float4 wb1 = *reinterpret_cast<const float4*>(wrow + (d + 1) * 128 + 64);
#pragma unroll
        for (int p = 0; p < 4; ++p) {
          float2 qv2 = *reinterpret_cast<const float2*>(&q_lds[ws + p][h_l * 34 + d]);
          u[p][0] = fmaf(wa0.x, qv2.x, u[p][0]);
          u[p][1] = fmaf(wa0.y, qv2.x, u[p][1]);
          u[p][2] = fmaf(wa0.z, qv2.x, u[p][2]);
          u[p][3] = fmaf(wa0.w, qv2.x, u[p][3]);
          u[p][4] = fmaf(wb0.x, qv2.x, u[p][4]);
          u[p][5] = fmaf(wb0.y, qv2.x, u[p][5]);
          u[p][6] = fmaf(wb0.z, qv2.x, u[p][6]);
          u[p][7] = fmaf(wb0.w, qv2.x, u[p][7]);
          u[p][0] = fmaf(wa1.x, qv2.y, u[p][0]);
          u[p][1] = fmaf(wa1.y, qv2.y, u[p][1]);
          u[p][2] = fmaf(wa1.z, qv2.y, u[p][2]);
          u[p][3] = fmaf(wa1.w, qv2.y, u[p][3]);
          u[p][4] = fmaf(wb1.x, qv2.y, u[p][4]);
          u[p][5] = fmaf(wb1.y, qv2.y, u[p][5]);
          u[p][6] = fmaf(wb1.z, qv2.y, u[p][6]);
          u[p][7] = fmaf(wb1.w, qv2.y, u[p][7]);
        }
      }
    }
    // ---- base[p] = qbk[p][i][h_l] - sum_c self[c]*u[c] ----
    float base[4];
#pragma unroll
    for (int p = 0; p < 4; ++p) {
      const float4* sp = reinterpret_cast<const float4*>(&self_lds[ws + p][4 * cg]);
      float4 sA = sp[0];
      float4 sB = sp[16];   // +64 floats
      float sd;
      sd = sA.x * u[p][0];
      sd = fmaf(sA.y, u[p][1], sd);
      sd = fmaf(sA.z, u[p][2], sd);
      sd = fmaf(sA.w, u[p][3], sd);
      sd = fmaf(sB.x, u[p][4], sd);
      sd = fmaf(sB.y, u[p][5], sd);
      sd = fmaf(sB.z, u[p][6], sd);
      sd = fmaf(sB.w, u[p][7], sd);
      sd = sum16(sd);
      base[p] = qbk_lds[ws + p][i * 4 + h_l] - sd;
    }
    // ---- logits: 16 rows, explicit 4-deep rolling register stage ----
#pragma unroll
    for (int p = 0; p < 4; ++p) {
      float4 sA[4], sB[4];
#define LOADROW(J, SLOT)                                                     \
  {                                                                          \
    int nb_ = __builtin_amdgcn_readlane(nidx[p], i * 16 + (J));              \
    const float* rp_ = pcd_b + (size_t)(unsigned)nb_ * 128 + 4 * cg;         \
    sA[(SLOT)] = *reinterpret_cast<const float4*>(rp_);                      \
    sB[(SLOT)] = *reinterpret_cast<const float4*>(rp_ + 64);                 \
  }
      LOADROW(0, 0) LOADROW(1, 1) LOADROW(2, 2) LOADROW(3, 3)
      float myl = 0.f;
#pragma unroll
      for (int jg = 0; jg < 4; ++jg) {
#pragma unroll
        for (int js = 0; js < 4; ++js) {
          const int j = jg * 4 + js;
          float4 nA = sA[js], nB = sB[js];
          if (jg < 3) LOADROW(j + 4, js)   // refill slot for group jg+1
          float pd;
          pd = nA.x * u[p][0];
          pd = fmaf(nA.y, u[p][1], pd);
          pd = fmaf(nA.z, u[p][2], pd);
          pd = fmaf(nA.w, u[p][3], pd);
          pd = fmaf(nB.x, u[p][4], pd);
          pd = fmaf(nB.y, u[p][5], pd);
          pd = fmaf(nB.z, u[p][6], pd);
          pd = fmaf(nB.w, u[p][7], pd);
          pd = sum16(pd);
          float lg = (pd + base[p]) * INV_SQRT_D;
          if (cg == j) myl = lg;
        }
      }
#undef LOADROW
      // softmax over the 16 lanes of this head group (all-VALU DPP)
      float m = max16(myl);
      float e = expf(myl - m);
      float swl = e * myl;
      float se = sum16(e);
      swl = sum16(swl);
      am[p] += swl / se;
    }
  }

  // ---- epilogue: out[pt_p, 2l+{0,1}] = attn[h_l] * v ----
#pragma unroll
  for (int p = 0; p < 4; ++p) {
    float2 o = make_float2(am[p] * va[p], am[p] * vb[p]);
    reinterpret_cast<float2*>(out + (size_t)(pt_base + p) * 128)[l] = o;
  }
}

// ---------------------------------------------------------------------------
extern "C" void kernel_launch(void* const* d_in, const int* in_sizes, int n_in,
                              void* d_out, int out_size, void* d_ws, size_t ws_size,
                              hipStream_t stream) {
  const float* pcd   = (const float*)d_in[0];
  const float* coord = (const float*)d_in[1];
  // d_in[2] = K (scalar int, fixed 16 — hardcoded)
  const float* Wq = (const float*)d_in[3];
  const float* bq = (const float*)d_in[4];
  const float* Wk = (const float*)d_in[5];
  const float* bk = (const float*)d_in[6];
  const float* Wv = (const float*)d_in[7];
  const float* bv = (const float*)d_in[8];
  float* out = (float*)d_out;

  // workspace layout
  int*   idx_ws = (int*)d_ws;                                   // 16384*48*4 = 3,145,728 B
  float* sq_ws  = (float*)((char*)d_ws + 3145728);              // 65,536 B
  float* wkT_ws = (float*)((char*)d_ws + 3211264);              // 196,608 B

  prep_kernel<<<192, 256, 0, stream>>>(coord, Wk, sq_ws, wkT_ws);
  topk5_kernel<<<NB_B * NB_N / 4, 256, 0, stream>>>(coord, sq_ws, idx_ws);
  main_kernel<<<NB_B * NB_N / 8, 128, 0, stream>>>(pcd, Wq, bq, bk, Wv, bv,
                                                   wkT_ws, idx_ws, out);
}